// Round 22
// baseline (22.349 us; speedup 1.0000x reference)
//
#include <hip/hip_runtime.h>
#include <hip/hip_bf16.h>

typedef __attribute__((ext_vector_type(8))) short bf16x8;
typedef __attribute__((ext_vector_type(4))) float f32x4;

#define NPIX 32768

__device__ __forceinline__ ushort f2bf(float f) {
    __hip_bfloat16 h = __float2bfloat16(f);   // single v_cvt, RNE
    ushort u; __builtin_memcpy(&u, &h, 2);
    return u;
}

// R21 (single fused kernel, merged fold, block-LDS weights) + 16 WAVES:
// 1024 threads, 8 px/wave -> 4 waves/SIMD (was 2), doubling latency-hiding
// interleave. Extra per-wave cost is only LDS B-fragment reads + wasted
// MFMA half-tiles (A rows 8..15 dup rows 0..7 via q8=r16&7; MfmaUtil ~3%
// so free). Weight repack per block unchanged (spread over 2x threads).
// Block = 2 image rows (128 px); wave = (row-half wv>>3, col-eighth wv&7).
// LDS: 16 arenas x 5120 @0 | W1s 32768 @81920 | W2s 18432 @114688
//   => 133120 B, 1 block/CU (16 waves/CU).
// Wave-private arenas (one barrier after weight+x staging, zero after):
//   phase A: xs bf16 [8 rows][512 B] @arena+0, swizzled
//   phase B: hs bf16 [8 rows][128 B] @arena+4096, swizzled
//   phase C: ks f32  [8 rows][148]   @arena+0 (4736 B; aliases xs+hs head
//            -- safe: written after all xs/hs LDS reads, per-wave in-order)
// XCD k owns image k for halo L2 locality.
__global__ __launch_bounds__(1024, 1) void fused_kernel(
        const float* __restrict__ x,
        const float* __restrict__ W1, const float* __restrict__ b1,
        const float* __restrict__ gamma, const float* __restrict__ beta,
        const float* __restrict__ mean, const float* __restrict__ var,
        const float* __restrict__ W2, const float* __restrict__ b2,
        float* __restrict__ ker, float* __restrict__ out) {
    __shared__ __align__(16) char smem[133120];
    const int t = threadIdx.x;
    const int wv = t >> 6, ln = t & 63;
    char* arena = smem + wv * 5120;
    char* w1s   = smem + 81920;                  // block-shared packed W1
    char* w2s   = smem + 114688;                 // block-shared packed W2
    const int bid = (int)blockIdx.x;
    const int img = bid & 7;                     // XCD k <- image k
    const int rp  = bid >> 3;                    // row pair 0..31
    const int i   = rp * 2 + (wv >> 3);          // image row of this wave
    const int lb  = img * 64 + i;                // b*64 + i
    const int j0  = (wv & 7) * 8;                // wave's first column
    const int pw  = lb * 64 + j0;                // wave's first pixel
    const int r16 = ln & 15, g = ln >> 4;
    const int q8  = r16 & 7;                     // A-row remap (dup 8..15)

    // ---- repack W1 -> w1s (2048 x 16B chunks, 2 per thread) ----
    #pragma unroll
    for (int m = 0; m < 2; m++) {
        int idx = m * 1024 + t;
        int ln2 = idx & 63, dt = (idx >> 6) & 3, kk = idx >> 8;
        int d = dt * 16 + (ln2 & 15);
        float sc = gamma[d] * rsqrtf(var[d] + 1e-3f);
        int cbase = kk * 32 + (ln2 >> 4) * 8;
        ushort tmp[8];
        #pragma unroll
        for (int cc = 0; cc < 8; cc++)
            tmp[cc] = f2bf(W1[(cbase + cc) * 64 + d] * sc);
        __builtin_memcpy(w1s + idx * 16, tmp, 16);
    }
    // ---- repack W2 -> w2s (1152 x 16B chunks) ----
    #pragma unroll
    for (int m = 0; m < 2; m++) {
        int idx = m * 1024 + t;
        if (idx < 1152) {
            int ln2 = idx & 63, rem = idx >> 6;   // rem < 18
            int et = rem % 9, kk = rem / 9;
            int e = et * 16 + (ln2 & 15);
            int dbase = kk * 32 + (ln2 >> 4) * 8;
            ushort tmp[8];
            #pragma unroll
            for (int cc = 0; cc < 8; cc++)
                tmp[cc] = f2bf(W2[(dbase + cc) * 144 + e]);
            __builtin_memcpy(w2s + idx * 16, tmp, 16);
        }
    }
    // ---- per-thread BN-folded bias (L1-hot 256B arrays) ----
    float b1fv[4];
    #pragma unroll
    for (int dt = 0; dt < 4; dt++) {
        int d = dt * 16 + r16;
        float sc = gamma[d] * rsqrtf(var[d] + 1e-3f);
        b1fv[dt] = (b1[d] - mean[d]) * sc + beta[d];
    }

    // ---- stage wave's 8 x-rows: f32 -> bf16, XOR-swizzled, local rows ----
    {
        const float4* xg = (const float4*)(x + (size_t)pw * 256);
        #pragma unroll
        for (int it = 0; it < 8; it++) {
            float4 v = xg[it * 64 + ln];
            ushort4 b4; b4.x = f2bf(v.x); b4.y = f2bf(v.y);
            b4.z = f2bf(v.z); b4.w = f2bf(v.w);
            int bcol = (ln * 8) ^ (it << 4);
            *(ushort4*)(arena + it * 512 + bcol) = b4;
        }
    }
    __syncthreads();   // w1s/w2s visible to all waves (x staging wave-private)

    // ---- GEMM1: 8 px x 64 d; A from arena xs (row q8), B from w1s ----
    f32x4 acc[4];
    #pragma unroll
    for (int dt = 0; dt < 4; dt++) {
        float bv = b1fv[dt];
        acc[dt] = (f32x4){bv, bv, bv, bv};
    }
    #pragma unroll
    for (int kk = 0; kk < 8; kk++) {
        int bcA = (kk * 64 + g * 16) ^ (q8 << 4);
        bf16x8 av = *(const bf16x8*)(arena + q8 * 512 + bcA);
        #pragma unroll
        for (int dt = 0; dt < 4; dt++) {
            bf16x8 bv = *(const bf16x8*)(w1s + (((kk * 4 + dt) << 6) + ln) * 16);
            acc[dt] = __builtin_amdgcn_mfma_f32_16x16x32_bf16(av, bv, acc[dt], 0, 0, 0);
        }
    }

    // relu -> bf16 -> hs (arena+4096, rows 0..7, swizzled); q>=8 discarded
    #pragma unroll
    for (int dt = 0; dt < 4; dt++) {
        #pragma unroll
        for (int r = 0; r < 4; r++) {
            int q = g * 4 + r;                        // C/D row
            if (q < 8) {
                int bcol = ((dt * 16 + r16) * 2) ^ (q << 4);
                *(ushort*)(arena + 4096 + q * 128 + bcol) = f2bf(fmaxf(acc[dt][r], 0.f));
            }
        }
    }

    // ---- invol window preload: latency hides under GEMM2 ----
    const f32x4* xv4 = (const f32x4*)x;
    const f32x4 z4 = {0.f, 0.f, 0.f, 0.f};
    f32x4 wa[3], wb[3], wc[3], wd[3];   // cols j-1, j, j+1, j+2
    #pragma unroll
    for (int r = 0; r < 3; r++) {
        int row = i + r - 1;
        bool rv = (unsigned)row < 64u;
        const size_t rb = (size_t)(lb + r - 1) * 64;
        wa[r] = (rv && j0 > 0) ? xv4[(rb + (j0 - 1)) * 64 + ln] : z4;
        wb[r] = rv ? xv4[(rb + j0) * 64 + ln] : z4;
        wc[r] = rv ? xv4[(rb + j0 + 1) * 64 + ln] : z4;   // j0+1 <= 57 < 64
        wd[r] = rv ? xv4[(rb + j0 + 2) * 64 + ln] : z4;   // j0+2 <= 58 < 64
    }

    // ---- GEMM2: 8 px x 144 e; A from hs (row q8), B from w2s ----
    f32x4 acc2[9];
    #pragma unroll
    for (int et = 0; et < 9; et++) {
        float bv = b2[et * 16 + r16];
        acc2[et] = (f32x4){bv, bv, bv, bv};
    }
    #pragma unroll
    for (int kk = 0; kk < 2; kk++) {
        int bcA = (kk * 64 + g * 16) ^ (q8 << 4);
        bf16x8 av = *(const bf16x8*)(arena + 4096 + q8 * 128 + bcA);
        #pragma unroll
        for (int et = 0; et < 9; et++) {
            bf16x8 bv = *(const bf16x8*)(w2s + (((kk * 9 + et) << 6) + ln) * 16);
            acc2[et] = __builtin_amdgcn_mfma_f32_16x16x32_bf16(av, bv, acc2[et], 0, 0, 0);
        }
    }

    // ---- ks: f32 transpose into wave arena (LDS only); acc2 dies here ----
    float* ksf = (float*)arena;                       // [8][148]
    #pragma unroll
    for (int et = 0; et < 9; et++) {
        #pragma unroll
        for (int r = 0; r < 4; r++) {
            int q = g * 4 + r;
            if (q < 8)
                ksf[q * 148 + et * 16 + r16] = acc2[et][r];
        }
    }

    // ---- involution: 4-column shift window, prefetch depth 2 ----
    const int s4 = (ln & 3) * 4;
    #pragma unroll
    for (int pp = 0; pp < 8; pp++) {
        const int j = j0 + pp;
        const float* kp = ksf + pp * 148 + s4;
        f32x4 o = {0.f, 0.f, 0.f, 0.f};
        #pragma unroll
        for (int r = 0; r < 3; r++) {
            o += (*(const f32x4*)(kp + (r * 3 + 0) * 16)) * wa[r];
            o += (*(const f32x4*)(kp + (r * 3 + 1) * 16)) * wb[r];
            o += (*(const f32x4*)(kp + (r * 3 + 2) * 16)) * wc[r];
        }
        __builtin_nontemporal_store(o, &((f32x4*)out)[(size_t)(lb * 64 + j) * 64 + ln]);
        #pragma unroll
        for (int r = 0; r < 3; r++) { wa[r] = wb[r]; wb[r] = wc[r]; wc[r] = wd[r]; }
        if (pp < 6) {
            const int jn = j + 3;                      // consumed at pp+2
            const bool cv = jn < 64;
            #pragma unroll
            for (int r = 0; r < 3; r++) {
                int row = i + r - 1;
                bool rv = (unsigned)row < 64u;
                wd[r] = (rv && cv)
                    ? xv4[((size_t)(lb + r - 1) * 64 + jn) * 64 + ln] : z4;
            }
        }
    }

    // ---- coalesced ker epilogue: ksf -> contiguous NT stores (288 f32x4) ----
    {
        float* kerW = ker + (size_t)pw * 144;   // wave's 1152 floats
        #pragma unroll
        for (int m = 0; m < 5; m++) {
            int fidx = m * 64 + ln;          // f32x4 index within wave region
            if (fidx < 288) {
                int row  = fidx / 36;        // px row 0..7
                int col4 = fidx - row * 36;  // f32x4 within row (144/4=36)
                f32x4 v = *(const f32x4*)(ksf + row * 148 + col4 * 4);
                __builtin_nontemporal_store(v, (f32x4*)(kerW + fidx * 4));
            }
        }
    }
}

extern "C" void kernel_launch(void* const* d_in, const int* in_sizes, int n_in,
                              void* d_out, int out_size, void* d_ws, size_t ws_size,
                              hipStream_t stream) {
    const float* x     = (const float*)d_in[0];
    const float* W1    = (const float*)d_in[1];
    const float* b1    = (const float*)d_in[2];
    const float* gamma = (const float*)d_in[3];
    const float* beta  = (const float*)d_in[4];
    const float* mmean = (const float*)d_in[5];
    const float* mvar  = (const float*)d_in[6];
    const float* W2    = (const float*)d_in[7];
    const float* b2    = (const float*)d_in[8];

    float* out_main = (float*)d_out;                 // (B,H,W,C)   = 8388608 f32
    float* out_ker  = (float*)d_out + 8388608;       // (B,H,W,144) = 4718592 f32

    fused_kernel<<<NPIX / 128, 1024, 0, stream>>>(
        x, W1, b1, gamma, beta, mmean, mvar, W2, b2, out_ker, out_main);
}

// Round 23
// 21.464 us; speedup vs baseline: 1.0412x; 1.0412x over previous
//
#include <hip/hip_runtime.h>
#include <hip/hip_bf16.h>

typedef __attribute__((ext_vector_type(8))) short bf16x8;
typedef __attribute__((ext_vector_type(4))) float f32x4;

#define NPIX 32768

__device__ __forceinline__ ushort f2bf(float f) {
    __hip_bfloat16 h = __float2bfloat16(f);   // single v_cvt, RNE
    ushort u; __builtin_memcpy(&u, &h, 2);
    return u;
}

// R21 + two de-lockstep reorderings:
//  (1) barrier moved BEFORE x staging (it only protects w1s/w2s; x staging
//      is wave-private LDS) -> wave skew develops from HBM latency variance
//      and phases mix across the CU instead of bursting in lockstep;
//  (2) invol window preload hoisted above GEMM1 (was above GEMM2): taps get
//      GEMM1+hs+GEMM2 (~50 MFMA) of latency cover instead of ~18.
// Geometry identical to R21: block = 2 rows / 128 px, 512 threads, 8 waves,
// wave = (row-half, col-quarter) 16 px end-to-end; merged fold (per-block
// weight repack into LDS); zero barriers after the single weight barrier.
// LDS: 8 arenas x 10240 @0 | W1s 32768 @81920 | W2s 18432 @114688
//   => 133120 B, 1 block/CU (8 waves/CU).
// Arena phases: xs bf16 [16][512B] @0 swz | hs bf16 [16][128B] @8192 swz |
//   ks f32 [16][148] @0 (aliases xs+hs; safe per-wave in-order LDS).
// XCD k owns image k for halo L2 locality.
__global__ __launch_bounds__(512, 1) void fused_kernel(
        const float* __restrict__ x,
        const float* __restrict__ W1, const float* __restrict__ b1,
        const float* __restrict__ gamma, const float* __restrict__ beta,
        const float* __restrict__ mean, const float* __restrict__ var,
        const float* __restrict__ W2, const float* __restrict__ b2,
        float* __restrict__ ker, float* __restrict__ out) {
    __shared__ __align__(16) char smem[133120];
    const int t = threadIdx.x;
    const int wv = t >> 6, ln = t & 63;
    char* arena = smem + wv * 10240;
    char* w1s   = smem + 81920;                  // block-shared packed W1
    char* w2s   = smem + 114688;                 // block-shared packed W2
    const int bid = (int)blockIdx.x;
    const int img = bid & 7;                     // XCD k <- image k
    const int rp  = bid >> 3;                    // row pair 0..31
    const int i   = rp * 2 + (wv >> 2);          // image row of this wave
    const int lb  = img * 64 + i;                // b*64 + i
    const int j0  = (wv & 3) * 16;               // wave's first column
    const int pw  = lb * 64 + j0;                // wave's first pixel
    const int r16 = ln & 15, g = ln >> 4;

    // ---- repack W1 -> w1s (2048 x 16B chunks, 4 per thread) ----
    #pragma unroll
    for (int m = 0; m < 4; m++) {
        int idx = m * 512 + t;
        int ln2 = idx & 63, dt = (idx >> 6) & 3, kk = idx >> 8;
        int d = dt * 16 + (ln2 & 15);
        float sc = gamma[d] * rsqrtf(var[d] + 1e-3f);
        int cbase = kk * 32 + (ln2 >> 4) * 8;
        ushort tmp[8];
        #pragma unroll
        for (int cc = 0; cc < 8; cc++)
            tmp[cc] = f2bf(W1[(cbase + cc) * 64 + d] * sc);
        __builtin_memcpy(w1s + idx * 16, tmp, 16);
    }
    // ---- repack W2 -> w2s (1152 x 16B chunks) ----
    #pragma unroll
    for (int m = 0; m < 3; m++) {
        int idx = m * 512 + t;
        if (idx < 1152) {
            int ln2 = idx & 63, rem = idx >> 6;   // rem < 18
            int et = rem % 9, kk = rem / 9;
            int e = et * 16 + (ln2 & 15);
            int dbase = kk * 32 + (ln2 >> 4) * 8;
            ushort tmp[8];
            #pragma unroll
            for (int cc = 0; cc < 8; cc++)
                tmp[cc] = f2bf(W2[(dbase + cc) * 144 + e]);
            __builtin_memcpy(w2s + idx * 16, tmp, 16);
        }
    }
    // ---- per-thread BN-folded bias (L1-hot 256B arrays) ----
    float b1fv[4];
    #pragma unroll
    for (int dt = 0; dt < 4; dt++) {
        int d = dt * 16 + r16;
        float sc = gamma[d] * rsqrtf(var[d] + 1e-3f);
        b1fv[dt] = (b1[d] - mean[d]) * sc + beta[d];
    }

    __syncthreads();   // w1s/w2s visible; everything after is wave-private

    // ---- stage wave's 16 x-rows: f32 -> bf16, XOR-swizzled, local rows ----
    {
        const float4* xg = (const float4*)(x + (size_t)pw * 256);
        #pragma unroll
        for (int it = 0; it < 16; it++) {
            float4 v = xg[it * 64 + ln];
            ushort4 b4; b4.x = f2bf(v.x); b4.y = f2bf(v.y);
            b4.z = f2bf(v.z); b4.w = f2bf(v.w);
            int bcol = (ln * 8) ^ ((it & 7) << 4);
            *(ushort4*)(arena + it * 512 + bcol) = b4;
        }
    }

    // ---- invol window preload (hoisted): hides under GEMM1+hs+GEMM2 ----
    const f32x4* xv4 = (const f32x4*)x;
    const f32x4 z4 = {0.f, 0.f, 0.f, 0.f};
    f32x4 wa[3], wb[3], wc[3], wd[3];   // cols j-1, j, j+1, j+2
    #pragma unroll
    for (int r = 0; r < 3; r++) {
        int row = i + r - 1;
        bool rv = (unsigned)row < 64u;
        const size_t rb = (size_t)(lb + r - 1) * 64;
        wa[r] = (rv && j0 > 0) ? xv4[(rb + (j0 - 1)) * 64 + ln] : z4;
        wb[r] = rv ? xv4[(rb + j0) * 64 + ln] : z4;
        wc[r] = rv ? xv4[(rb + j0 + 1) * 64 + ln] : z4;   // j0+1 <= 49 < 64
        wd[r] = rv ? xv4[(rb + j0 + 2) * 64 + ln] : z4;   // j0+2 <= 50 < 64
    }

    // ---- GEMM1: 16 px x 64 d; A from arena xs, B from w1s (LDS) ----
    f32x4 acc[4];
    #pragma unroll
    for (int dt = 0; dt < 4; dt++) {
        float bv = b1fv[dt];
        acc[dt] = (f32x4){bv, bv, bv, bv};
    }
    #pragma unroll
    for (int kk = 0; kk < 8; kk++) {
        int bcA = (kk * 64 + g * 16) ^ ((r16 & 7) << 4);
        bf16x8 av = *(const bf16x8*)(arena + r16 * 512 + bcA);
        #pragma unroll
        for (int dt = 0; dt < 4; dt++) {
            bf16x8 bv = *(const bf16x8*)(w1s + (((kk * 4 + dt) << 6) + ln) * 16);
            acc[dt] = __builtin_amdgcn_mfma_f32_16x16x32_bf16(av, bv, acc[dt], 0, 0, 0);
        }
    }

    // relu -> bf16 -> hs (arena+8192, local rows 0..15, swizzled)
    #pragma unroll
    for (int dt = 0; dt < 4; dt++) {
        #pragma unroll
        for (int r = 0; r < 4; r++) {
            int q = g * 4 + r;                        // local px (C/D row)
            int bcol = ((dt * 16 + r16) * 2) ^ ((q & 7) << 4);
            *(ushort*)(arena + 8192 + q * 128 + bcol) = f2bf(fmaxf(acc[dt][r], 0.f));
        }
    }

    // ---- GEMM2: 16 px x 144 e; A from hs, B from w2s (LDS) ----
    f32x4 acc2[9];
    #pragma unroll
    for (int et = 0; et < 9; et++) {
        float bv = b2[et * 16 + r16];
        acc2[et] = (f32x4){bv, bv, bv, bv};
    }
    #pragma unroll
    for (int kk = 0; kk < 2; kk++) {
        int bcA = (kk * 64 + g * 16) ^ ((r16 & 7) << 4);
        bf16x8 av = *(const bf16x8*)(arena + 8192 + r16 * 128 + bcA);
        #pragma unroll
        for (int et = 0; et < 9; et++) {
            bf16x8 bv = *(const bf16x8*)(w2s + (((kk * 9 + et) << 6) + ln) * 16);
            acc2[et] = __builtin_amdgcn_mfma_f32_16x16x32_bf16(av, bv, acc2[et], 0, 0, 0);
        }
    }

    // ---- ks: f32 transpose into wave arena (LDS only); acc2 dies here ----
    float* ksf = (float*)arena;                       // [16][148]
    #pragma unroll
    for (int et = 0; et < 9; et++) {
        #pragma unroll
        for (int r = 0; r < 4; r++) {
            int q = g * 4 + r;
            ksf[q * 148 + et * 16 + r16] = acc2[et][r];
        }
    }

    // ---- involution: 4-column shift window, prefetch depth 2 ----
    const int s4 = (ln & 3) * 4;
    #pragma unroll 4
    for (int pp = 0; pp < 16; pp++) {
        const int j = j0 + pp;
        const float* kp = ksf + pp * 148 + s4;
        f32x4 o = {0.f, 0.f, 0.f, 0.f};
        #pragma unroll
        for (int r = 0; r < 3; r++) {
            o += (*(const f32x4*)(kp + (r * 3 + 0) * 16)) * wa[r];
            o += (*(const f32x4*)(kp + (r * 3 + 1) * 16)) * wb[r];
            o += (*(const f32x4*)(kp + (r * 3 + 2) * 16)) * wc[r];
        }
        __builtin_nontemporal_store(o, &((f32x4*)out)[(size_t)(lb * 64 + j) * 64 + ln]);
        #pragma unroll
        for (int r = 0; r < 3; r++) { wa[r] = wb[r]; wb[r] = wc[r]; wc[r] = wd[r]; }
        if (pp < 14) {
            const int jn = j + 3;                      // consumed at pp+2
            const bool cv = jn < 64;
            #pragma unroll
            for (int r = 0; r < 3; r++) {
                int row = i + r - 1;
                bool rv = (unsigned)row < 64u;
                wd[r] = (rv && cv)
                    ? xv4[((size_t)(lb + r - 1) * 64 + jn) * 64 + ln] : z4;
            }
        }
    }

    // ---- coalesced ker epilogue: ksf -> 9 x 1KB contiguous NT stores ----
    {
        float* kerW = ker + (size_t)pw * 144;   // wave's 2304 floats
        #pragma unroll
        for (int m = 0; m < 9; m++) {
            int fidx = m * 64 + ln;          // f32x4 index within wave region
            int row  = fidx / 36;            // px row 0..15
            int col4 = fidx - row * 36;      // f32x4 within row (144/4=36)
            f32x4 v = *(const f32x4*)(ksf + row * 148 + col4 * 4);
            __builtin_nontemporal_store(v, (f32x4*)(kerW + fidx * 4));
        }
    }
}

extern "C" void kernel_launch(void* const* d_in, const int* in_sizes, int n_in,
                              void* d_out, int out_size, void* d_ws, size_t ws_size,
                              hipStream_t stream) {
    const float* x     = (const float*)d_in[0];
    const float* W1    = (const float*)d_in[1];
    const float* b1    = (const float*)d_in[2];
    const float* gamma = (const float*)d_in[3];
    const float* beta  = (const float*)d_in[4];
    const float* mmean = (const float*)d_in[5];
    const float* mvar  = (const float*)d_in[6];
    const float* W2    = (const float*)d_in[7];
    const float* b2    = (const float*)d_in[8];

    float* out_main = (float*)d_out;                 // (B,H,W,C)   = 8388608 f32
    float* out_ker  = (float*)d_out + 8388608;       // (B,H,W,144) = 4718592 f32

    fused_kernel<<<NPIX / 128, 512, 0, stream>>>(
        x, W1, b1, gamma, beta, mmean, mvar, W2, b2, out_ker, out_main);
}